// Round 1
// baseline (1544.093 us; speedup 1.0000x reference)
//
#include <hip/hip_runtime.h>

#define SPATIAL 110592   // 48*48*48
#define CH 160
#define NTOT (CH*SPATIAL)
#define EPSV 1e-5f

__device__ __forceinline__ float gelu_f(float v){
    return 0.5f*v*(1.0f + erff(v*0.70710678118654752f));
}

__device__ __forceinline__ void block_reduce2_atomic(float v0, float v1,
                                                     float* d0, float* d1){
    #pragma unroll
    for (int off = 32; off > 0; off >>= 1){
        v0 += __shfl_down(v0, off);
        v1 += __shfl_down(v1, off);
    }
    __shared__ float s0[4], s1[4];
    int wv = threadIdx.x >> 6, lane = threadIdx.x & 63;
    if (lane == 0){ s0[wv] = v0; s1[wv] = v1; }
    __syncthreads();
    if (threadIdx.x == 0){
        atomicAdd(d0, s0[0]+s0[1]+s0[2]+s0[3]);
        atomicAdd(d1, s1[0]+s1[1]+s1[2]+s1[3]);
    }
}

// conv1x1: out[o][s] = b[o] + sum_c w[o*CH+c]*x[c][s]; optional GN stats accum
template<int OTILE, bool STATS>
__global__ __launch_bounds__(256)
void conv_kernel(const float* __restrict__ x, const float* __restrict__ w,
                 const float* __restrict__ b, float* __restrict__ out,
                 float* __restrict__ stats){
    int s  = blockIdx.x*256 + threadIdx.x;
    int ob = blockIdx.y*OTILE;
    float acc[OTILE];
    #pragma unroll
    for (int o = 0; o < OTILE; ++o) acc[o] = 0.f;
    #pragma unroll 2
    for (int c = 0; c < CH; ++c){
        float xv = x[c*SPATIAL + s];
        #pragma unroll
        for (int o = 0; o < OTILE; ++o)
            acc[o] = fmaf(w[(ob+o)*CH + c], xv, acc[o]);
    }
    float lsum = 0.f, lsq = 0.f;
    #pragma unroll
    for (int o = 0; o < OTILE; ++o){
        float v = acc[o] + b[ob+o];
        out[(ob+o)*SPATIAL + s] = v;
        if (STATS){ lsum += v; lsq += v*v; }
    }
    if (STATS) block_reduce2_atomic(lsum, lsq, stats, stats+1);
}

// GroupNorm(1) affine + exact GELU, elementwise, float4
__global__ __launch_bounds__(256)
void gn_gelu_kernel(const float* __restrict__ h, const float* __restrict__ g,
                    const float* __restrict__ be, const float* __restrict__ stats,
                    float* __restrict__ out){
    const float inv_n = 1.0f/(float)NTOT;
    float mu  = stats[0]*inv_n;
    float var = stats[1]*inv_n - mu*mu;
    float rs  = rsqrtf(var + EPSV);
    int nvec = NTOT/4;
    for (int i = blockIdx.x*256 + threadIdx.x; i < nvec; i += gridDim.x*256){
        int c = (i*4)/SPATIAL;           // SPATIAL % 4 == 0 -> uniform per float4
        float sc = rs*g[c];
        float sh = be[c] - mu*sc;
        float4 v = ((const float4*)h)[i];
        v.x = gelu_f(fmaf(v.x, sc, sh));
        v.y = gelu_f(fmaf(v.y, sc, sh));
        v.z = gelu_f(fmaf(v.z, sc, sh));
        v.w = gelu_f(fmaf(v.w, sc, sh));
        ((float4*)out)[i] = v;
    }
}

// fused: three axial-shifted conv1x1 (+bias) -> gelu each -> sum; GN2 stats accum
__global__ __launch_bounds__(256)
void shift_conv3_kernel(const float* __restrict__ A,
                        const float* __restrict__ w21, const float* __restrict__ b21,
                        const float* __restrict__ w22, const float* __restrict__ b22,
                        const float* __restrict__ w23, const float* __restrict__ b23,
                        float* __restrict__ out, float* __restrict__ stats){
    int s   = blockIdx.x*256 + threadIdx.x;
    int d   = s / 2304;
    int rem = s - d*2304;
    int hh  = rem / 48;
    int ww  = rem - hh*48;
    int ob  = blockIdx.y*32;
    float a1[32], a2[32], a3[32];
    #pragma unroll
    for (int o = 0; o < 32; ++o){ a1[o]=0.f; a2[o]=0.f; a3[o]=0.f; }
    for (int c = 0; c < CH; ++c){
        int sh = (c >> 5) - 2;            // chunk shift in [-2,2]
        int idx = c*SPATIAL + s;
        float xlr = 0.f, xtd = 0.f, xdp = 0.f;
        int dd = d  - sh; if (dd >= 0 && dd < 48) xlr = A[idx - sh*2304];
        int h2 = hh - sh; if (h2 >= 0 && h2 < 48) xtd = A[idx - sh*48];
        int w2 = ww - sh; if (w2 >= 0 && w2 < 48) xdp = A[idx - sh];
        #pragma unroll
        for (int o = 0; o < 32; ++o){
            a1[o] = fmaf(w21[(ob+o)*CH + c], xlr, a1[o]);
            a2[o] = fmaf(w22[(ob+o)*CH + c], xtd, a2[o]);
            a3[o] = fmaf(w23[(ob+o)*CH + c], xdp, a3[o]);
        }
    }
    float lsum = 0.f, lsq = 0.f;
    #pragma unroll
    for (int o = 0; o < 32; ++o){
        float v = gelu_f(a1[o] + b21[ob+o])
                + gelu_f(a2[o] + b22[ob+o])
                + gelu_f(a3[o] + b23[ob+o]);
        out[(ob+o)*SPATIAL + s] = v;
        lsum += v; lsq += v*v;
    }
    block_reduce2_atomic(lsum, lsq, stats+2, stats+3);
}

// fold GN2 (per-channel affine from global stats) into w3/b3
__global__ void fold_kernel(const float* __restrict__ w3, const float* __restrict__ b3,
                            const float* __restrict__ g2, const float* __restrict__ be2,
                            const float* __restrict__ stats,
                            float* __restrict__ w3p, float* __restrict__ b3p){
    __shared__ float a_sh[CH], d_sh[CH];
    const float inv_n = 1.0f/(float)NTOT;
    float mu  = stats[2]*inv_n;
    float var = stats[3]*inv_n - mu*mu;
    float rs  = rsqrtf(var + EPSV);
    for (int c = threadIdx.x; c < CH; c += blockDim.x){
        float a = rs*g2[c];
        a_sh[c] = a;
        d_sh[c] = be2[c] - mu*a;
    }
    __syncthreads();
    for (int i = threadIdx.x; i < CH*CH; i += blockDim.x){
        int c = i % CH;
        w3p[i] = w3[i]*a_sh[c];
    }
    for (int o = threadIdx.x; o < CH; o += blockDim.x){
        float acc = b3[o];
        for (int c = 0; c < CH; ++c) acc += w3[o*CH + c]*d_sh[c];
        b3p[o] = acc;
    }
}

extern "C" void kernel_launch(void* const* d_in, const int* in_sizes, int n_in,
                              void* d_out, int out_size, void* d_ws, size_t ws_size,
                              hipStream_t stream){
    const float* x   = (const float*)d_in[0];
    const float* w1  = (const float*)d_in[1];
    const float* b1  = (const float*)d_in[2];
    const float* g1  = (const float*)d_in[3];
    const float* be1 = (const float*)d_in[4];
    const float* w21 = (const float*)d_in[5];
    const float* b21 = (const float*)d_in[6];
    const float* w22 = (const float*)d_in[7];
    const float* b22 = (const float*)d_in[8];
    const float* w23 = (const float*)d_in[9];
    const float* b23 = (const float*)d_in[10];
    const float* g2  = (const float*)d_in[11];
    const float* be2 = (const float*)d_in[12];
    const float* w3  = (const float*)d_in[13];
    const float* b3  = (const float*)d_in[14];

    float* buf1  = (float*)d_ws;          // h1, later h2 (NTOT floats)
    float* buf2  = buf1 + NTOT;           // gelu(gn(h1)) (NTOT floats)
    float* stats = buf2 + NTOT;           // 4 floats: sum1,sumsq1,sum2,sumsq2
    float* w3p   = stats + 8;
    float* b3p   = w3p + CH*CH;

    hipMemsetAsync(stats, 0, 4*sizeof(float), stream);

    dim3 blk(256);
    conv_kernel<80, true><<<dim3(432, 2), blk, 0, stream>>>(x, w1, b1, buf1, stats);
    gn_gelu_kernel<<<dim3(2048), blk, 0, stream>>>(buf1, g1, be1, stats, buf2);
    shift_conv3_kernel<<<dim3(432, 5), blk, 0, stream>>>(buf2, w21, b21, w22, b22,
                                                         w23, b23, buf1, stats);
    fold_kernel<<<dim3(1), blk, 0, stream>>>(w3, b3, g2, be2, stats, w3p, b3p);
    conv_kernel<80, false><<<dim3(432, 2), blk, 0, stream>>>(buf1, w3p, b3p,
                                                             (float*)d_out, nullptr);
}

// Round 2
// 745.479 us; speedup vs baseline: 2.0713x; 2.0713x over previous
//
#include <hip/hip_runtime.h>

#define SPATIAL 110592   // 48*48*48
#define CH 160
#define NTOT (CH*SPATIAL)
#define EPSV 1e-5f

__device__ __forceinline__ float gelu_f(float v){
    return 0.5f*v*(1.0f + erff(v*0.70710678118654752f));
}

__device__ __forceinline__ void block_reduce2_atomic(float v0, float v1,
                                                     float* d0, float* d1){
    #pragma unroll
    for (int off = 32; off > 0; off >>= 1){
        v0 += __shfl_down(v0, off);
        v1 += __shfl_down(v1, off);
    }
    __shared__ float s0[4], s1[4];
    int wv = threadIdx.x >> 6, lane = threadIdx.x & 63;
    if (lane == 0){ s0[wv] = v0; s1[wv] = v1; }
    __syncthreads();
    if (threadIdx.x == 0){
        atomicAdd(d0, s0[0]+s0[1]+s0[2]+s0[3]);
        atomicAdd(d1, s1[0]+s1[1]+s1[2]+s1[3]);
    }
}

// transpose the 4 static weight matrices: wT[c*CH+o] = w[o*CH+c]
__global__ __launch_bounds__(256)
void transpose4(const float* __restrict__ a0, const float* __restrict__ a1,
                const float* __restrict__ a2, const float* __restrict__ a3,
                float* __restrict__ t0, float* __restrict__ t1,
                float* __restrict__ t2, float* __restrict__ t3){
    const float* src[4] = {a0,a1,a2,a3};
    float*       dst[4] = {t0,t1,t2,t3};
    int m = blockIdx.y;
    int i = blockIdx.x*256 + threadIdx.x;
    if (i < CH*CH){
        int o = i/CH, c = i - o*CH;
        dst[m][c*CH + o] = src[m][i];
    }
}

// conv1x1 with transposed weights: out[o][s] = b[o] + sum_c wT[c][o]*x[c][s]
// grid: 1D 2160 blocks (432 spatial x 5 o-tiles), XCD-swizzled.
template<bool STATS>
__global__ __launch_bounds__(256, 4)
void conv_kernel(const float* __restrict__ x, const float* __restrict__ wT,
                 const float* __restrict__ b, float* __restrict__ out,
                 float* __restrict__ stats){
    int virt = (blockIdx.x & 7)*270 + (blockIdx.x >> 3);   // 2160 = 8*270 bijective
    int xb = virt / 5, yo = virt - xb*5;
    int s  = xb*256 + threadIdx.x;
    int ob = yo*32;

    float acc[32];
    #pragma unroll
    for (int o = 0; o < 32; ++o) acc[o] = 0.f;

    float xv = x[s];                     // c = 0
    for (int c = 0; c < CH-1; ++c){
        float xn = x[(c+1)*SPATIAL + s]; // prefetch next channel
        const float* wc = wT + c*CH + ob;
        #pragma unroll
        for (int o = 0; o < 32; ++o)
            acc[o] = fmaf(wc[o], xv, acc[o]);
        xv = xn;
    }
    {   // last channel
        const float* wc = wT + (CH-1)*CH + ob;
        #pragma unroll
        for (int o = 0; o < 32; ++o)
            acc[o] = fmaf(wc[o], xv, acc[o]);
    }

    float lsum = 0.f, lsq = 0.f;
    #pragma unroll
    for (int o = 0; o < 32; ++o){
        float v = acc[o] + b[ob+o];
        out[(ob+o)*SPATIAL + s] = v;
        if (STATS){ lsum += v; lsq += v*v; }
    }
    if (STATS) block_reduce2_atomic(lsum, lsq, stats, stats+1);
}

// GroupNorm(1) affine + exact GELU, elementwise, float4
__global__ __launch_bounds__(256)
void gn_gelu_kernel(const float* __restrict__ h, const float* __restrict__ g,
                    const float* __restrict__ be, const float* __restrict__ stats,
                    float* __restrict__ out){
    const float inv_n = 1.0f/(float)NTOT;
    float mu  = stats[0]*inv_n;
    float var = stats[1]*inv_n - mu*mu;
    float rs  = rsqrtf(var + EPSV);
    int nvec = NTOT/4;
    for (int i = blockIdx.x*256 + threadIdx.x; i < nvec; i += gridDim.x*256){
        int c = (i*4)/SPATIAL;           // SPATIAL % 4 == 0 -> uniform per float4
        float sc = rs*g[c];
        float sh = be[c] - mu*sc;
        float4 v = ((const float4*)h)[i];
        v.x = gelu_f(fmaf(v.x, sc, sh));
        v.y = gelu_f(fmaf(v.y, sc, sh));
        v.z = gelu_f(fmaf(v.z, sc, sh));
        v.w = gelu_f(fmaf(v.w, sc, sh));
        ((float4*)out)[i] = v;
    }
}

// fused: three axial-shifted conv1x1 (+bias) -> gelu each -> sum; GN2 stats accum
// grid: 1D 2160 blocks, XCD-swizzled. Transposed weights.
__global__ __launch_bounds__(256, 2)
void shift_conv3_kernel(const float* __restrict__ A,
                        const float* __restrict__ w21T, const float* __restrict__ b21,
                        const float* __restrict__ w22T, const float* __restrict__ b22,
                        const float* __restrict__ w23T, const float* __restrict__ b23,
                        float* __restrict__ out, float* __restrict__ stats){
    int virt = (blockIdx.x & 7)*270 + (blockIdx.x >> 3);
    int xb = virt / 5, yo = virt - xb*5;
    int s  = xb*256 + threadIdx.x;
    int ob = yo*32;

    int d   = s / 2304;                  // uniform within block (2304 % 256 == 0)
    int rem = s - d*2304;
    int hh  = rem / 48;
    int ww  = rem - hh*48;

    float a1[32], a2[32], a3[32];
    #pragma unroll
    for (int o = 0; o < 32; ++o){ a1[o]=0.f; a2[o]=0.f; a3[o]=0.f; }

#define LOADC(cc, RL, RT, RD) { \
        int sh_  = ((cc) >> 5) - 2; \
        int bas_ = (cc)*SPATIAL + s; \
        RL = ((unsigned)(d  - sh_) < 48u) ? A[bas_ - sh_*2304] : 0.f; \
        RT = ((unsigned)(hh - sh_) < 48u) ? A[bas_ - sh_*48]   : 0.f; \
        RD = ((unsigned)(ww - sh_) < 48u) ? A[bas_ - sh_]      : 0.f; \
    }
#define FMA32(cc, XL, XT, XD) { \
        const float* c1_ = w21T + (cc)*CH + ob; \
        const float* c2_ = w22T + (cc)*CH + ob; \
        const float* c3_ = w23T + (cc)*CH + ob; \
        _Pragma("unroll") \
        for (int o = 0; o < 32; ++o){ \
            a1[o] = fmaf(c1_[o], XL, a1[o]); \
            a2[o] = fmaf(c2_[o], XT, a2[o]); \
            a3[o] = fmaf(c3_[o], XD, a3[o]); \
        } \
    }

    float l0,t0,p0, l1,t1,p1;
    LOADC(0, l0,t0,p0);
    LOADC(1, l1,t1,p1);
    for (int c = 0; c < CH; c += 2){
        float nl0=0.f,nt0=0.f,np0=0.f, nl1=0.f,nt1=0.f,np1=0.f;
        if (c + 2 < CH){                 // wave-uniform branch
            LOADC(c+2, nl0,nt0,np0);
            LOADC(c+3, nl1,nt1,np1);
        }
        FMA32(c,   l0,t0,p0);
        FMA32(c+1, l1,t1,p1);
        l0=nl0; t0=nt0; p0=np0;
        l1=nl1; t1=nt1; p1=np1;
    }
#undef LOADC
#undef FMA32

    float lsum = 0.f, lsq = 0.f;
    #pragma unroll
    for (int o = 0; o < 32; ++o){
        float v = gelu_f(a1[o] + b21[ob+o])
                + gelu_f(a2[o] + b22[ob+o])
                + gelu_f(a3[o] + b23[ob+o]);
        out[(ob+o)*SPATIAL + s] = v;
        lsum += v; lsq += v*v;
    }
    block_reduce2_atomic(lsum, lsq, stats+2, stats+3);
}

// fold GN2 (per-channel affine from global stats) into w3/b3; writes TRANSPOSED w3
__global__ void fold_kernel(const float* __restrict__ w3, const float* __restrict__ b3,
                            const float* __restrict__ g2, const float* __restrict__ be2,
                            const float* __restrict__ stats,
                            float* __restrict__ w3pT, float* __restrict__ b3p){
    __shared__ float a_sh[CH], d_sh[CH];
    const float inv_n = 1.0f/(float)NTOT;
    float mu  = stats[2]*inv_n;
    float var = stats[3]*inv_n - mu*mu;
    float rs  = rsqrtf(var + EPSV);
    for (int c = threadIdx.x; c < CH; c += blockDim.x){
        float a = rs*g2[c];
        a_sh[c] = a;
        d_sh[c] = be2[c] - mu*a;
    }
    __syncthreads();
    for (int i = threadIdx.x; i < CH*CH; i += blockDim.x){
        int c = i / CH, o = i - c*CH;        // output index: wT[c][o]
        w3pT[i] = w3[o*CH + c]*a_sh[c];
    }
    for (int o = threadIdx.x; o < CH; o += blockDim.x){
        float acc = b3[o];
        for (int c = 0; c < CH; ++c) acc += w3[o*CH + c]*d_sh[c];
        b3p[o] = acc;
    }
}

extern "C" void kernel_launch(void* const* d_in, const int* in_sizes, int n_in,
                              void* d_out, int out_size, void* d_ws, size_t ws_size,
                              hipStream_t stream){
    const float* x   = (const float*)d_in[0];
    const float* w1  = (const float*)d_in[1];
    const float* b1  = (const float*)d_in[2];
    const float* g1  = (const float*)d_in[3];
    const float* be1 = (const float*)d_in[4];
    const float* w21 = (const float*)d_in[5];
    const float* b21 = (const float*)d_in[6];
    const float* w22 = (const float*)d_in[7];
    const float* b22 = (const float*)d_in[8];
    const float* w23 = (const float*)d_in[9];
    const float* b23 = (const float*)d_in[10];
    const float* g2  = (const float*)d_in[11];
    const float* be2 = (const float*)d_in[12];
    const float* w3  = (const float*)d_in[13];
    const float* b3  = (const float*)d_in[14];

    float* buf1  = (float*)d_ws;          // h1, later h2 (NTOT floats)
    float* buf2  = buf1 + NTOT;           // gelu(gn(h1)) (NTOT floats)
    float* stats = buf2 + NTOT;           // 4 floats (pad to 8)
    float* w1T   = stats + 8;
    float* w21T  = w1T  + CH*CH;
    float* w22T  = w21T + CH*CH;
    float* w23T  = w22T + CH*CH;
    float* w3pT  = w23T + CH*CH;
    float* b3p   = w3pT + CH*CH;

    hipMemsetAsync(stats, 0, 4*sizeof(float), stream);

    dim3 blk(256);
    transpose4<<<dim3(100, 4), blk, 0, stream>>>(w1, w21, w22, w23,
                                                 w1T, w21T, w22T, w23T);
    conv_kernel<true><<<dim3(2160), blk, 0, stream>>>(x, w1T, b1, buf1, stats);
    gn_gelu_kernel<<<dim3(2048), blk, 0, stream>>>(buf1, g1, be1, stats, buf2);
    shift_conv3_kernel<<<dim3(2160), blk, 0, stream>>>(buf2, w21T, b21, w22T, b22,
                                                       w23T, b23, buf1, stats);
    fold_kernel<<<dim3(1), blk, 0, stream>>>(w3, b3, g2, be2, stats, w3pT, b3p);
    conv_kernel<false><<<dim3(2160), blk, 0, stream>>>(buf1, w3pT, b3p,
                                                       (float*)d_out, nullptr);
}

// Round 3
// 646.600 us; speedup vs baseline: 2.3880x; 1.1529x over previous
//
#include <hip/hip_runtime.h>

#define SPATIAL 110592   // 48*48*48
#define CH 160
#define NTOT (CH*SPATIAL)
#define EPSV 1e-5f
#define NCHUNK 20              // 160/8 k-chunks of 8
#define WPAD 161               // padded o-dim per chunk
#define WELEMS (NCHUNK*WPAD*8) // 25760 ushort per weight matrix
#define W16 (WELEMS/8)         // 3220 short8 chunks
#define NTILE 128
#define NBLK (SPATIAL/NTILE)   // 864

typedef __attribute__((ext_vector_type(8))) short short8;
typedef __attribute__((ext_vector_type(4))) float f32x4;

__device__ __forceinline__ ushort f2bf(float f){
    union { float f; unsigned u; } v; v.f = f;
    return (ushort)((v.u + 0x7FFFu + ((v.u >> 16) & 1u)) >> 16);  // RNE
}
__device__ __forceinline__ float gelu_f(float v){
    return 0.5f*v*(1.0f + erff(v*0.70710678118654752f));
}

__device__ __forceinline__ void block_reduce2_atomic(float v0, float v1,
                                                     float* d0, float* d1){
    #pragma unroll
    for (int off = 32; off > 0; off >>= 1){
        v0 += __shfl_down(v0, off);
        v1 += __shfl_down(v1, off);
    }
    __shared__ float s0[4], s1[4];
    int wv = threadIdx.x >> 6, lane = threadIdx.x & 63;
    if (lane == 0){ s0[wv] = v0; s1[wv] = v1; }
    __syncthreads();
    if (threadIdx.x == 0){
        atomicAdd(d0, s0[0]+s0[1]+s0[2]+s0[3]);
        atomicAdd(d1, s1[0]+s1[1]+s1[2]+s1[3]);
    }
}

// convert W[o][c] fp32 -> bf16 chunk layout: dst[(cc*WPAD + o)*8 + i] = bf16(W[o][cc*8+i])
__global__ __launch_bounds__(256)
void prep_weights(const float* __restrict__ w0, const float* __restrict__ w1,
                  const float* __restrict__ w2, const float* __restrict__ w3,
                  ushort* __restrict__ o0, ushort* __restrict__ o1,
                  ushort* __restrict__ o2, ushort* __restrict__ o3){
    const float* src[4] = {w0,w1,w2,w3};
    ushort*      dst[4] = {o0,o1,o2,o3};
    int m = blockIdx.y;
    int e = blockIdx.x*256 + threadIdx.x;
    if (e >= WELEMS) return;
    int cc  = e / (WPAD*8);
    int rem = e - cc*(WPAD*8);
    int o = rem >> 3, i = rem & 7;
    dst[m][e] = (o < CH) ? f2bf(src[m][o*CH + cc*8 + i]) : (ushort)0;
}

// conv1x1 via MFMA: out[o][s] = bias[o] + sum_c W[o][c] * X[c][s]
// TIN: float (convert) or ushort (bf16 passthrough). TOUT: float or ushort(bf16).
template<typename TIN, typename TOUT, bool STATS>
__global__ __launch_bounds__(256, 2)
void conv_mfma(const TIN* __restrict__ xin, const ushort* __restrict__ wbf,
               const float* __restrict__ bias, TOUT* __restrict__ out,
               float* __restrict__ stats){
    __shared__ short8 WL[W16];
    __shared__ ushort XS[2][NTILE][40];

    int t = threadIdx.x;
    int s_base = blockIdx.x*NTILE;
    int s_loc = t & (NTILE-1);
    int c0 = (t >> 7) * 16;             // 0 or 16
    int sg = s_base + s_loc;

    // weights -> LDS (linear copy, L2-hot)
    const short8* ws8 = (const short8*)wbf;
    for (int k = t; k < W16; k += 256) WL[k] = ws8[k];

    int l = t & 63, wv = t >> 6;
    int lg = l >> 4, ln = l & 15;
    int cb = wv*32;

    f32x4 acc[10][2];
    #pragma unroll
    for (int mt = 0; mt < 10; ++mt){ acc[mt][0] = (f32x4)0.f; acc[mt][1] = (f32x4)0.f; }

    auto stage = [&](int ks, int buf){
        int base = (ks*32 + c0)*SPATIAL + sg;
        short8 lo, hi;
        #pragma unroll
        for (int i = 0; i < 8; ++i){
            if constexpr (sizeof(TIN) == 4) lo[i] = (short)f2bf((float)xin[base + i*SPATIAL]);
            else                            lo[i] = (short)xin[base + i*SPATIAL];
        }
        #pragma unroll
        for (int i = 0; i < 8; ++i){
            if constexpr (sizeof(TIN) == 4) hi[i] = (short)f2bf((float)xin[base + (8+i)*SPATIAL]);
            else                            hi[i] = (short)xin[base + (8+i)*SPATIAL];
        }
        *(short8*)&XS[buf][s_loc][c0]     = lo;
        *(short8*)&XS[buf][s_loc][c0 + 8] = hi;
    };

    stage(0, 0);
    __syncthreads();
    #pragma unroll
    for (int ks = 0; ks < 5; ++ks){
        if (ks < 4) stage(ks+1, (ks+1)&1);
        int cur = ks & 1;
        short8 bf0 = *(const short8*)&XS[cur][cb + ln][lg*8];
        short8 bf1 = *(const short8*)&XS[cur][cb + 16 + ln][lg*8];
        #pragma unroll
        for (int mt = 0; mt < 10; ++mt){
            short8 af = WL[(ks*4 + lg)*WPAD + mt*16 + ln];
            acc[mt][0] = __builtin_amdgcn_mfma_f32_16x16x32_bf16(af, bf0, acc[mt][0], 0,0,0);
            acc[mt][1] = __builtin_amdgcn_mfma_f32_16x16x32_bf16(af, bf1, acc[mt][1], 0,0,0);
        }
        __syncthreads();
    }

    float lsum = 0.f, lsq = 0.f;
    #pragma unroll
    for (int mt = 0; mt < 10; ++mt){
        #pragma unroll
        for (int ns = 0; ns < 2; ++ns){
            int sc = s_base + cb + ns*16 + ln;
            int o0 = mt*16 + lg*4;
            #pragma unroll
            for (int r = 0; r < 4; ++r){
                float v = acc[mt][ns][r] + bias[o0 + r];
                if constexpr (sizeof(TOUT) == 4) out[(o0+r)*SPATIAL + sc] = v;
                else                             out[(o0+r)*SPATIAL + sc] = f2bf(v);
                if (STATS){ lsum += v; lsq += v*v; }
            }
        }
    }
    if (STATS) block_reduce2_atomic(lsum, lsq, stats, stats+1);
}

// GN1 affine + exact GELU, fp32 in -> bf16 out
__global__ __launch_bounds__(256)
void gn_gelu(const float* __restrict__ h, const float* __restrict__ g,
             const float* __restrict__ be, const float* __restrict__ stats,
             ushort* __restrict__ out){
    const float inv_n = 1.0f/(float)NTOT;
    float mu  = stats[0]*inv_n;
    float var = stats[1]*inv_n - mu*mu;
    float rs  = rsqrtf(var + EPSV);
    int nvec = NTOT/4;
    for (int i = blockIdx.x*256 + threadIdx.x; i < nvec; i += gridDim.x*256){
        int c = (i*4)/SPATIAL;               // uniform per float4
        float sc = rs*g[c];
        float sh = be[c] - mu*sc;
        float4 v = ((const float4*)h)[i];
        ushort4 o;
        o.x = f2bf(gelu_f(fmaf(v.x, sc, sh)));
        o.y = f2bf(gelu_f(fmaf(v.y, sc, sh)));
        o.z = f2bf(gelu_f(fmaf(v.z, sc, sh)));
        o.w = f2bf(gelu_f(fmaf(v.w, sc, sh)));
        ((ushort4*)out)[i] = o;
    }
}

// 3 shifted conv1x1 branches (sequential, shared LDS), gelu each, sum; GN2 stats
__global__ __launch_bounds__(256, 2)
void shift_conv3_mfma(const ushort* __restrict__ A,
                      const ushort* __restrict__ w21, const float* __restrict__ b21,
                      const ushort* __restrict__ w22, const float* __restrict__ b22,
                      const ushort* __restrict__ w23, const float* __restrict__ b23,
                      ushort* __restrict__ out, float* __restrict__ stats){
    __shared__ short8 WL[W16];
    __shared__ ushort XS[2][NTILE][40];

    int t = threadIdx.x;
    int s_base = blockIdx.x*NTILE;
    int s_loc = t & (NTILE-1);
    int c0 = (t >> 7) * 16;
    int sg = s_base + s_loc;
    int d   = sg / 2304;
    int rem = sg - d*2304;
    int hh  = rem / 48;
    int ww  = rem - hh*48;

    int l = t & 63, wv = t >> 6;
    int lg = l >> 4, ln = l & 15;
    int cb = wv*32;

    f32x4 sum[10][2];
    #pragma unroll
    for (int mt = 0; mt < 10; ++mt){ sum[mt][0] = (f32x4)0.f; sum[mt][1] = (f32x4)0.f; }

    auto run_branch = [&](const ushort* __restrict__ wb, const float* __restrict__ bb,
                          int AS, int crd){
        const short8* ws8 = (const short8*)wb;
        for (int k = t; k < W16; k += 256) WL[k] = ws8[k];

        f32x4 acc[10][2];
        #pragma unroll
        for (int mt = 0; mt < 10; ++mt){ acc[mt][0] = (f32x4)0.f; acc[mt][1] = (f32x4)0.f; }

        auto stage = [&](int ks, int buf){
            int sh = ks - 2;
            bool inb = ((unsigned)(crd - sh) < 48u);
            int base = (ks*32 + c0)*SPATIAL + sg - sh*AS;
            short8 lo, hi;
            #pragma unroll
            for (int i = 0; i < 8; ++i) lo[i] = inb ? (short)A[base + i*SPATIAL] : (short)0;
            #pragma unroll
            for (int i = 0; i < 8; ++i) hi[i] = inb ? (short)A[base + (8+i)*SPATIAL] : (short)0;
            *(short8*)&XS[buf][s_loc][c0]     = lo;
            *(short8*)&XS[buf][s_loc][c0 + 8] = hi;
        };

        stage(0, 0);
        __syncthreads();
        #pragma unroll
        for (int ks = 0; ks < 5; ++ks){
            if (ks < 4) stage(ks+1, (ks+1)&1);
            int cur = ks & 1;
            short8 bf0 = *(const short8*)&XS[cur][cb + ln][lg*8];
            short8 bf1 = *(const short8*)&XS[cur][cb + 16 + ln][lg*8];
            #pragma unroll
            for (int mt = 0; mt < 10; ++mt){
                short8 af = WL[(ks*4 + lg)*WPAD + mt*16 + ln];
                acc[mt][0] = __builtin_amdgcn_mfma_f32_16x16x32_bf16(af, bf0, acc[mt][0], 0,0,0);
                acc[mt][1] = __builtin_amdgcn_mfma_f32_16x16x32_bf16(af, bf1, acc[mt][1], 0,0,0);
            }
            __syncthreads();
        }
        #pragma unroll
        for (int mt = 0; mt < 10; ++mt){
            #pragma unroll
            for (int ns = 0; ns < 2; ++ns){
                int o0 = mt*16 + lg*4;
                #pragma unroll
                for (int r = 0; r < 4; ++r)
                    sum[mt][ns][r] += gelu_f(acc[mt][ns][r] + bb[o0 + r]);
            }
        }
    };

    run_branch(w21, b21, 2304, d);
    run_branch(w22, b22, 48,   hh);
    run_branch(w23, b23, 1,    ww);

    float lsum = 0.f, lsq = 0.f;
    #pragma unroll
    for (int mt = 0; mt < 10; ++mt){
        #pragma unroll
        for (int ns = 0; ns < 2; ++ns){
            int sc = s_base + cb + ns*16 + ln;
            int o0 = mt*16 + lg*4;
            #pragma unroll
            for (int r = 0; r < 4; ++r){
                float v = sum[mt][ns][r];
                lsum += v; lsq += v*v;
                out[(o0+r)*SPATIAL + sc] = f2bf(v);
            }
        }
    }
    block_reduce2_atomic(lsum, lsq, stats+2, stats+3);
}

// fold GN2 affine into w3/b3; emit w3 in bf16 chunk layout
__global__ void fold_conv3(const float* __restrict__ w3, const float* __restrict__ b3,
                           const float* __restrict__ g2, const float* __restrict__ be2,
                           const float* __restrict__ stats,
                           ushort* __restrict__ w3bf, float* __restrict__ b3p){
    __shared__ float a_sh[CH], d_sh[CH];
    const float inv_n = 1.0f/(float)NTOT;
    float mu  = stats[2]*inv_n;
    float var = stats[3]*inv_n - mu*mu;
    float rs  = rsqrtf(var + EPSV);
    for (int c = threadIdx.x; c < CH; c += blockDim.x){
        float a = rs*g2[c];
        a_sh[c] = a;
        d_sh[c] = be2[c] - mu*a;
    }
    __syncthreads();
    for (int e = threadIdx.x; e < WELEMS; e += blockDim.x){
        int cc  = e / (WPAD*8);
        int rem = e - cc*(WPAD*8);
        int o = rem >> 3, i = rem & 7;
        int c = cc*8 + i;
        w3bf[e] = (o < CH) ? f2bf(w3[o*CH + c]*a_sh[c]) : (ushort)0;
    }
    for (int o = threadIdx.x; o < CH; o += blockDim.x){
        float acc = b3[o];
        for (int c = 0; c < CH; ++c) acc += w3[o*CH + c]*d_sh[c];
        b3p[o] = acc;
    }
}

extern "C" void kernel_launch(void* const* d_in, const int* in_sizes, int n_in,
                              void* d_out, int out_size, void* d_ws, size_t ws_size,
                              hipStream_t stream){
    const float* x   = (const float*)d_in[0];
    const float* w1  = (const float*)d_in[1];
    const float* b1  = (const float*)d_in[2];
    const float* g1  = (const float*)d_in[3];
    const float* be1 = (const float*)d_in[4];
    const float* w21 = (const float*)d_in[5];
    const float* b21 = (const float*)d_in[6];
    const float* w22 = (const float*)d_in[7];
    const float* b22 = (const float*)d_in[8];
    const float* w23 = (const float*)d_in[9];
    const float* b23 = (const float*)d_in[10];
    const float* g2  = (const float*)d_in[11];
    const float* be2 = (const float*)d_in[12];
    const float* w3  = (const float*)d_in[13];
    const float* b3  = (const float*)d_in[14];

    float*  buf1  = (float*)d_ws;                 // h1 fp32 (NTOT), later reused as buf3
    ushort* buf2  = (ushort*)(buf1 + NTOT);       // gelu(gn(h1)) bf16 (NTOT)
    float*  stats = (float*)(buf2 + NTOT);        // 4 fp32 (pad 8)
    ushort* w1bf  = (ushort*)(stats + 8);
    ushort* w21bf = w1bf  + WELEMS;
    ushort* w22bf = w21bf + WELEMS;
    ushort* w23bf = w22bf + WELEMS;
    ushort* w3bf  = w23bf + WELEMS;
    float*  b3p   = (float*)(w3bf + WELEMS);
    ushort* buf3  = (ushort*)buf1;                // h2 bf16 (NTOT), overlays dead buf1

    hipMemsetAsync(stats, 0, 4*sizeof(float), stream);

    dim3 blk(256);
    prep_weights<<<dim3((WELEMS+255)/256, 4), blk, 0, stream>>>(
        w1, w21, w22, w23, w1bf, w21bf, w22bf, w23bf);
    conv_mfma<float, float, true><<<dim3(NBLK), blk, 0, stream>>>(
        x, w1bf, b1, buf1, stats);
    gn_gelu<<<dim3(2048), blk, 0, stream>>>(buf1, g1, be1, stats, buf2);
    shift_conv3_mfma<<<dim3(NBLK), blk, 0, stream>>>(
        buf2, w21bf, b21, w22bf, b22, w23bf, b23, buf3, stats);
    fold_conv3<<<dim3(1), blk, 0, stream>>>(w3, b3, g2, be2, stats, w3bf, b3p);
    conv_mfma<ushort, float, false><<<dim3(NBLK), blk, 0, stream>>>(
        buf3, w3bf, b3p, (float*)d_out, nullptr);
}